// Round 3
// baseline (134.897 us; speedup 1.0000x reference)
//
#include <hip/hip_runtime.h>
#include <hip/hip_bf16.h>

// SoftRAM attention: S=128, B=256 bits, H=16 heads, NB=12 bits/neuron, PB=7.
// addr(i,j,h,n) = aq[i] | ak[j] | ap[i-j] (disjoint bit groups, connections
// fixed per (h,n)); only sign(memory) matters -> 512B bit-LUT per (h,n).
//
// R3: latency-bound fix. Grid 256x1024 -> 2048x256 (2 heads/block, 8 blocks/CU,
// 32 waves/CU = 100% slots). Each wave handles (head, j-parity): even-j trip
// count is uniformly 65, odd-j 64, under the i0=lane / i1=127-lane pairing.
// 3 kernels: pack tokens -> main (per-(n,hp) head-count bytes) -> majority.

#define S 128
#define B 256
#define H 16
#define NB 12

// ---- kernel 0: pack token bits into ws_tok[128][8] dwords (4 KB) ----
__global__ __launch_bounds__(256) void softram_pack(
    const int* __restrict__ tokens, unsigned int* __restrict__ ws_tok)
{
    const int tid = threadIdx.x;            // 0..255, 4 dwords each
    const int4* tp = (const int4*)tokens;
    #pragma unroll
    for (int q = 0; q < 4; ++q) {
        int e = tid + (q << 8);             // 0..1023
        int i = e >> 3, w = e & 7;
        unsigned int v = 0;
        #pragma unroll
        for (int u = 0; u < 8; ++u) {
            int4 x = tp[i * 64 + w * 8 + u];
            v |= (unsigned int)(x.x & 1) << (4 * u + 0);
            v |= (unsigned int)(x.y & 1) << (4 * u + 1);
            v |= (unsigned int)(x.z & 1) << (4 * u + 2);
            v |= (unsigned int)(x.w & 1) << (4 * u + 3);
        }
        ws_tok[e] = v;
    }
}

// ---- kernel 1: main. block (n, hp) handles heads {2hp, 2hp+1} ----
__global__ __launch_bounds__(256, 8) void softram_main(
    const float* __restrict__ memory,        // [H,B,4096]
    const int* __restrict__ connections,     // [H,B,NB]
    const unsigned int* __restrict__ ws_tok, // [128][8]
    unsigned char* __restrict__ ws_cnt)      // [8][256][128]
{
    const int bx  = blockIdx.x;
    const int n   = bx & 255;
    const int hp  = bx >> 8;                // 0..7
    const int tid = threadIdx.x;            // 0..255

    __shared__ unsigned int   lut[2][128];       // 1 KB: sign bits, 2 heads
    __shared__ unsigned int   tok[S * 8];        // 4 KB: packed tokens
    __shared__ unsigned short aqs[2][S], aks[2][S], aps[2][S];  // 1.5 KB
    __shared__ int            conns[2][NB];
    __shared__ unsigned short partial[2][2][S];  // [head][jparity][i]: 1 KB

    // Phase B: LUT sign-pack. 2 heads x 128 dwords = 256 slots, 1/thread.
    {
        int hh = tid >> 7, d = tid & 127;
        const float4* mrow =
            (const float4*)(memory + ((size_t)((((hp << 1) | hh) << 8) | n) << 12));
        unsigned int w = 0;
        #pragma unroll
        for (int u = 0; u < 8; ++u) {
            float4 v = mrow[(d << 3) + u];
            w |= (unsigned int)(v.x > 0.f) << (4 * u + 0);
            w |= (unsigned int)(v.y > 0.f) << (4 * u + 1);
            w |= (unsigned int)(v.z > 0.f) << (4 * u + 2);
            w |= (unsigned int)(v.w > 0.f) << (4 * u + 3);
        }
        lut[hh][d] = w;
    }

    // Phase A: packed tokens ws -> LDS (1024 dwords, 4/thread).
    #pragma unroll
    for (int q = 0; q < 4; ++q)
        tok[tid + (q << 8)] = ws_tok[tid + (q << 8)];

    if (tid < 2 * NB) {
        int hh = tid / NB, b = tid - hh * NB;
        conns[hh][b] = connections[((hp << 1) | hh) * (B * NB) + n * NB + b];
    }

    __syncthreads();

    // Phase C: aq/ak/ap tables, 2 heads x 128 = 256 entries, 1/thread.
    // conns[hh][b] is wave-uniform per 128-thread half -> uniform branches.
    {
        int hh = tid >> 7, ii = tid & 127;
        unsigned int aq = 0, ak = 0, ap = 0;
        #pragma unroll
        for (int b = 0; b < NB; ++b) {
            int c = conns[hh][b];
            if (c < 256) {
                aq |= ((tok[ii * 8 + (c >> 5)] >> (c & 31)) & 1u) << b;
            } else if (c < 512) {
                int c2 = c - 256;
                ak |= ((tok[ii * 8 + (c2 >> 5)] >> (c2 & 31)) & 1u) << b;
            } else {
                ap |= (unsigned int)((ii >> (c - 512)) & 1) << b;
            }
        }
        aqs[hh][ii] = (unsigned short)aq;
        aks[hh][ii] = (unsigned short)ak;
        aps[hh][ii] = (unsigned short)ap;
    }

    __syncthreads();

    // Phase D: wave = (local head hh, j-parity r). Lane owns i0=lane, i1=127-lane.
    // Even-j (r=0): uniform 65 iters; odd-j (r=1): uniform 64.
    const int wave = tid >> 6, lane = tid & 63;
    const int hh = wave >> 1, r = wave & 1;
    const int i0 = lane, i1 = 127 - lane;
    const int c0 = (lane - r >= 0) ? (((lane - r) >> 1) + 1) : 0;  // #j==r mod2, j<=i0
    const int ctot = 65 - r;

    const unsigned int aq0 = aqs[hh][i0];
    const unsigned int aq1 = aqs[hh][i1];
    const unsigned short* __restrict__ akrow = &aks[hh][0];
    const unsigned short* __restrict__ aprow = &aps[hh][0];
    const unsigned int* __restrict__ lrow = &lut[hh][0];

    unsigned int p0 = 0, p1 = 0;
    #pragma unroll 8
    for (int k = 0; k < ctot; ++k) {
        bool first = (k < c0);
        int jf = r + 2 * k;                       // j if still on i0
        int j  = first ? jf : (jf - 2 * c0);      // restart j sequence for i1
        int ii = first ? i0 : i1;
        int imj = ii - j;
        unsigned int aqv = first ? aq0 : aq1;
        unsigned int addr = aqv | (unsigned int)akrow[j] | (unsigned int)aprow[imj];
        unsigned int bit = (lrow[addr >> 5] >> (addr & 31)) & 1u;
        p0 ^= first ? bit : 0u;
        p1 ^= first ? 0u : bit;
    }
    partial[hh][r][i0] = (unsigned short)p0;
    partial[hh][r][i1] = (unsigned short)p1;

    __syncthreads();

    // Epilogue: per-i count of set head-parities for this head pair -> ws.
    if (tid < S) {
        int cnt = (partial[0][0][tid] ^ partial[0][1][tid])
                + (partial[1][0][tid] ^ partial[1][1][tid]);
        ws_cnt[(hp * 256 + n) * 128 + tid] = (unsigned char)cnt;
    }
}

// ---- kernel 2: majority vote across the 8 head-pairs ----
__global__ __launch_bounds__(256) void softram_reduce(
    const unsigned char* __restrict__ ws_cnt, int* __restrict__ out)
{
    const int i = blockIdx.x;    // 0..127
    const int n = threadIdx.x;   // 0..255
    int tot = 0;
    #pragma unroll
    for (int hp = 0; hp < 8; ++hp)
        tot += ws_cnt[(hp * 256 + n) * 128 + i];
    out[i * B + n] = (tot > (H / 2)) ? 1 : 0;
}

extern "C" void kernel_launch(void* const* d_in, const int* in_sizes, int n_in,
                              void* d_out, int out_size, void* d_ws, size_t ws_size,
                              hipStream_t stream) {
    const int*   tokens      = (const int*)d_in[0];
    const float* memory      = (const float*)d_in[1];
    const int*   connections = (const int*)d_in[2];
    int*         out         = (int*)d_out;
    (void)in_sizes; (void)n_in; (void)out_size; (void)ws_size;

    unsigned int*  ws_tok = (unsigned int*)d_ws;                  // 4 KB
    unsigned char* ws_cnt = (unsigned char*)d_ws + 4096;          // 256 KB

    softram_pack<<<1, 256, 0, stream>>>(tokens, ws_tok);
    softram_main<<<8 * B, 256, 0, stream>>>(memory, connections, ws_tok, ws_cnt);
    softram_reduce<<<S, 256, 0, stream>>>(ws_cnt, out);
}